// Round 1
// baseline (172.233 us; speedup 1.0000x reference)
//
#include <hip/hip_runtime.h>
#include <math.h>

// EUNN layer, H=1024, 16 steps of even+odd pairwise complex rotations + final phase.
// Kernel 1 precomputes rotation coefficients (trig) into d_ws.
// Kernel 2: one wave per row-group (R rows), lane l owns elements 16l..16l+15
// (8 float4 = 8 even pairs). Even rotations register-local; odd rotations
// register-local except one boundary pair per lane handled via intra-wave shfl.
//
// ws layout (float offsets):
//   evnA  : float4 [16][512]           @ 0       (dr,di,or,oi)
//   evnB  : float2 [16][512]           @ 32768   (st,ct)
//   oddA  : float4 [16][512]           @ 49152   (entry 511 = identity 1,0,0,0)
//   oddBp : float2 [16][520]           @ 81920   (entry k holds pair k-1; k=0 -> 0,1)
//   omcs  : float2 [1024]              @ 98560   (cos w, sin w)
// total 100608 floats = 402432 bytes

#define EVNA_OFF 0
#define EVNB_OFF 32768
#define ODDA_OFF 49152
#define ODDB_OFF 81920
#define OMCS_OFF 98560

__global__ void eunn_precompute(const float* __restrict__ omega,
                                const float* __restrict__ et,
                                const float* __restrict__ ot,
                                const float* __restrict__ ep,
                                const float* __restrict__ op,
                                float* __restrict__ ws) {
    int tid = blockIdx.x * blockDim.x + threadIdx.x;   // 0..8191
    int s = tid >> 9;
    int j = tid & 511;
    float4* evnA  = (float4*)(ws + EVNA_OFF);
    float2* evnB  = (float2*)(ws + EVNB_OFF);
    float4* oddA  = (float4*)(ws + ODDA_OFF);
    float2* oddBp = (float2*)(ws + ODDB_OFF);
    float2* omcs  = (float2*)(ws + OMCS_OFF);

    // even pair (s, j)
    float st, ct, sp, cp;
    sincosf(et[s * 512 + j], &st, &ct);
    sincosf(ep[s * 512 + j], &sp, &cp);
    evnA[s * 512 + j] = make_float4(sp * ct, cp * ct, -sp * st, -cp * st);
    evnB[s * 512 + j] = make_float2(st, ct);

    // odd pair (s, j) for j < 511; j == 511 writes identity pads
    if (j < 511) {
        sincosf(ot[s * 511 + j], &st, &ct);
        sincosf(op[s * 511 + j], &sp, &cp);
        oddA[s * 512 + j] = make_float4(sp * ct, cp * ct, -sp * st, -cp * st);
        oddBp[s * 520 + j + 1] = make_float2(st, ct);
    } else {
        oddA[s * 512 + 511]  = make_float4(1.f, 0.f, 0.f, 0.f);  // pair 511: identity
        oddBp[s * 520 + 0]   = make_float2(0.f, 1.f);            // pair -1: identity
        oddBp[s * 520 + 512] = make_float2(0.f, 1.f);            // unused pad
    }

    if (tid < 1024) {
        float sw, cw;
        sincosf(omega[tid], &sw, &cw);
        omcs[tid] = make_float2(cw, sw);
    }
}

template <int R>
__global__ __launch_bounds__(256) void eunn_main(const float* __restrict__ x,
                                                 float* __restrict__ out,
                                                 const float* __restrict__ ws) {
    const int lane = threadIdx.x & 63;
    const int wid  = blockIdx.x * (blockDim.x >> 6) + (threadIdx.x >> 6);

    const float4* evnA   = (const float4*)(ws + EVNA_OFF);
    const float4* evnB4  = (const float4*)(ws + EVNB_OFF);  // 2 float2 per float4
    const float4* oddA   = (const float4*)(ws + ODDA_OFF);
    const float4* oddB4  = (const float4*)(ws + ODDB_OFF);
    const float4* omcs4  = (const float4*)(ws + OMCS_OFF);

    // e[r][p] = (re[16l+2p], im[16l+2p], re[16l+2p+1], im[16l+2p+1])
    float4 e[R][8];
#pragma unroll
    for (int r = 0; r < R; ++r) {
        const float4* xr = (const float4*)(x + (size_t)(wid * R + r) * 2048) + lane * 8;
#pragma unroll
        for (int p = 0; p < 8; ++p) e[r][p] = xr[p];
    }

#pragma unroll 1
    for (int s = 0; s < 16; ++s) {
        float4 A[8];
        float4 B[4];
        // ---------------- even rotation ----------------
        {
            const float4* eA = evnA + s * 512 + lane * 8;
            const float4* eB = evnB4 + s * 256 + lane * 4;
#pragma unroll
            for (int p = 0; p < 8; ++p) A[p] = eA[p];
#pragma unroll
            for (int q = 0; q < 4; ++q) B[q] = eB[q];
#pragma unroll
            for (int r = 0; r < R; ++r) {
#pragma unroll
                for (int p = 0; p < 8; ++p) {
                    float4 v = e[r][p];
                    float4 a = A[p];
                    float bx = (p & 1) ? B[p >> 1].z : B[p >> 1].x;
                    float by = (p & 1) ? B[p >> 1].w : B[p >> 1].y;
                    float n0r = a.x * v.x - a.y * v.y + a.z * v.z - a.w * v.w;
                    float n0i = a.y * v.x + a.x * v.y + a.w * v.z + a.z * v.w;
                    float n1r = bx * v.x + by * v.z;
                    float n1i = bx * v.y + by * v.w;
                    e[r][p] = make_float4(n0r, n0i, n1r, n1i);
                }
            }
        }
        // ---------------- odd rotation ----------------
        {
            const float4* oA = oddA + s * 512 + lane * 8;
            const float4* oB = oddB4 + s * 260 + lane * 4;
#pragma unroll
            for (int p = 0; p < 8; ++p) A[p] = oA[p];
#pragma unroll
            for (int q = 0; q < 4; ++q) B[q] = oB[q];
#pragma unroll
            for (int r = 0; r < R; ++r) {
                // neighbor exchange (pre-update values)
                float upx = __shfl_down(e[r][0].x, 1, 64);  // elem 16l+16 re
                float upy = __shfl_down(e[r][0].y, 1, 64);  // elem 16l+16 im
                float dnz = __shfl_up(e[r][7].z, 1, 64);    // elem 16l-1 re
                float dnw = __shfl_up(e[r][7].w, 1, 64);    // elem 16l-1 im
                // elem[16l]: second half of pair (8l-1); coeffs at oddBp[8l] = B[0].xy
                {
                    float n1r = B[0].x * dnz + B[0].y * e[r][0].x;
                    float n1i = B[0].x * dnw + B[0].y * e[r][0].y;
                    e[r][0].x = n1r;
                    e[r][0].y = n1i;
                }
                // interior odd pairs j = 8l+p, p = 0..6: (elem 16l+2p+1, 16l+2p+2)
#pragma unroll
                for (int p = 0; p < 7; ++p) {
                    float4 a = A[p];
                    int k = p + 1;  // oddBp local entry for pair j
                    float bx = (k & 1) ? B[k >> 1].z : B[k >> 1].x;
                    float by = (k & 1) ? B[k >> 1].w : B[k >> 1].y;
                    float e0r = e[r][p].z, e0i = e[r][p].w;
                    float e1r = e[r][p + 1].x, e1i = e[r][p + 1].y;
                    e[r][p].z     = a.x * e0r - a.y * e0i + a.z * e1r - a.w * e1i;
                    e[r][p].w     = a.y * e0r + a.x * e0i + a.w * e1r + a.z * e1i;
                    e[r][p + 1].x = bx * e0r + by * e1r;
                    e[r][p + 1].y = bx * e0i + by * e1i;
                }
                // boundary pair j = 8l+7: (elem 16l+15, elem 16l+16 via shfl)
                {
                    float4 a = A[7];
                    float e0r = e[r][7].z, e0i = e[r][7].w;
                    e[r][7].z = a.x * e0r - a.y * e0i + a.z * upx - a.w * upy;
                    e[r][7].w = a.y * e0r + a.x * e0i + a.w * upx + a.z * upy;
                }
            }
        }
    }

    // ---------------- final diagonal phase + store ----------------
    float4 W[8];
#pragma unroll
    for (int p = 0; p < 8; ++p) W[p] = omcs4[lane * 8 + p];  // (c,s,c,s)
#pragma unroll
    for (int r = 0; r < R; ++r) {
        float4* outr = (float4*)(out + (size_t)(wid * R + r) * 2048) + lane * 8;
#pragma unroll
        for (int p = 0; p < 8; ++p) {
            float4 v = e[r][p];
            float4 w = W[p];
            outr[p] = make_float4(v.x * w.x - v.y * w.y,
                                  v.x * w.y + v.y * w.x,
                                  v.z * w.z - v.w * w.w,
                                  v.z * w.w + v.w * w.z);
        }
    }
}

extern "C" void kernel_launch(void* const* d_in, const int* in_sizes, int n_in,
                              void* d_out, int out_size, void* d_ws, size_t ws_size,
                              hipStream_t stream) {
    const float* x     = (const float*)d_in[0];  // (4096,1024,2)
    const float* omega = (const float*)d_in[1];  // (1024,)
    const float* et    = (const float*)d_in[2];  // (16,512)
    const float* ot    = (const float*)d_in[3];  // (16,511)
    const float* ep    = (const float*)d_in[4];  // (16,512)
    const float* op    = (const float*)d_in[5];  // (16,511)
    float* out = (float*)d_out;
    float* ws  = (float*)d_ws;

    eunn_precompute<<<dim3(32), dim3(256), 0, stream>>>(omega, et, ot, ep, op, ws);

    // R=2 rows per wave: 2048 waves, 4 waves/block -> 512 blocks
    eunn_main<2><<<dim3(512), dim3(256), 0, stream>>>(x, out, ws);
}